// Round 1
// baseline (303.915 us; speedup 1.0000x reference)
//
#include <hip/hip_runtime.h>
#include <stdint.h>
#include <stddef.h>

#define SS 1024
#define BB 16
#define DD 512
#define HH 8
#define DHH 64

typedef __attribute__((ext_vector_type(8))) short bf16x8;
typedef __attribute__((ext_vector_type(4))) float f32x4;
typedef __attribute__((ext_vector_type(4))) float float4v;
typedef __attribute__((ext_vector_type(4))) unsigned short us4;

__device__ __forceinline__ unsigned short f2bf(float f) {
  union { float f; unsigned int u; } v; v.f = f;
  unsigned int x = v.u;
  return (unsigned short)((x + 0x7FFFu + ((x >> 16) & 1u)) >> 16);
}

// async global->LDS, 16B per lane; LDS dest must be wave-uniform base (+lane*16 implicit)
#define GLDS16(dst, src)                                                                  \
  __builtin_amdgcn_global_load_lds(                                                      \
      (const __attribute__((address_space(1))) unsigned int*)(const void*)(src),         \
      (__attribute__((address_space(3))) unsigned int*)(void*)(dst), 16, 0, 0)

// ---------------- Kernel A: f32 -> bf16 conversion (x and the 3 weight stacks) --------
__global__ void cvt_kernel(const float* __restrict__ x,
                           const float* __restrict__ wq,
                           const float* __restrict__ wk,
                           const float* __restrict__ wv,
                           unsigned short* __restrict__ xb,
                           unsigned short* __restrict__ wb) {
  const int i = blockIdx.x * 256 + threadIdx.x;   // one float4 per thread
  const int n_x4 = (SS * BB * DD) / 4;            // 2,097,152
  if (i < n_x4) {
    float4v v = ((const float4v*)x)[i];
    us4 o;
    o[0] = f2bf(v[0]); o[1] = f2bf(v[1]); o[2] = f2bf(v[2]); o[3] = f2bf(v[3]);
    ((us4*)xb)[i] = o;
  } else {
    const int j = i - n_x4;            // 0..196607
    const int sel = j >> 16;           // which weight (65536 float4 each)
    const int off4 = j & 65535;
    const float* wsrc = (sel == 0) ? wq : ((sel == 1) ? wk : wv);
    float4v v = ((const float4v*)wsrc)[off4];
    us4 o;
    o[0] = f2bf(v[0]); o[1] = f2bf(v[1]); o[2] = f2bf(v[2]); o[3] = f2bf(v[3]);
    ((us4*)wb)[(sel << 16) + off4] = o;
  }
}

// ---------------- Kernel B: projection GEMM  Y[s,f] = sum_d x[s,b,d] * w[f,d] ---------
// grid: (8 M-tiles, 4 N-tiles, 48 = b*3+wsel). 128x128 tile, BK=32, 4 waves of 64x64.
// Outputs: wsel 0/1 -> q/k as [bh][s][e] bf16 ; wsel 2 -> vT as [bh][e][s] bf16.
__global__ __launch_bounds__(256) void proj_kernel(
    const unsigned short* __restrict__ xb,
    const unsigned short* __restrict__ wb,
    unsigned short* __restrict__ qb,
    unsigned short* __restrict__ kb,
    unsigned short* __restrict__ vt) {
  const int bm = blockIdx.x * 128;
  const int bn = blockIdx.y * 128;
  const int b = blockIdx.z / 3;
  const int wsel = blockIdx.z % 3;

  __shared__ unsigned short At[128 * 32];
  __shared__ unsigned short Bt[128 * 32];
  __shared__ unsigned short OT[4][64 * 72];   // per-wave 64x64 transpose pad +8

  const int tid = threadIdx.x;
  const int w = tid >> 6;
  const int lane = tid & 63;

  const unsigned short* wptr = wb + wsel * (512 * DD);

  f32x4 acc[4][4];
#pragma unroll
  for (int mi = 0; mi < 4; ++mi)
#pragma unroll
    for (int ni = 0; ni < 4; ++ni) acc[mi][ni] = (f32x4){0.f, 0.f, 0.f, 0.f};

  const int m0 = (w & 1) * 64;
  const int n0 = (w >> 1) * 64;

  for (int kt = 0; kt < 16; ++kt) {
#pragma unroll
    for (int i = 0; i < 2; ++i) {
      const int idx8 = i * 256 + tid;        // 0..511 : r = idx8/4, c8 = idx8%4
      const int r = idx8 >> 2;
      const int c8 = idx8 & 3;
      GLDS16(&At[(i * 256 + w * 64) * 8],
             xb + (size_t)(bm + r) * (BB * DD) + b * DD + kt * 32 + c8 * 8);
      GLDS16(&Bt[(i * 256 + w * 64) * 8],
             wptr + (size_t)(bn + r) * DD + kt * 32 + c8 * 8);
    }
    __syncthreads();
    bf16x8 af[4], bfr[4];
#pragma unroll
    for (int mi = 0; mi < 4; ++mi)
      af[mi] = *(const bf16x8*)&At[(m0 + mi * 16 + (lane & 15)) * 32 + (lane >> 4) * 8];
#pragma unroll
    for (int ni = 0; ni < 4; ++ni)
      bfr[ni] = *(const bf16x8*)&Bt[(n0 + ni * 16 + (lane & 15)) * 32 + (lane >> 4) * 8];
#pragma unroll
    for (int mi = 0; mi < 4; ++mi)
#pragma unroll
      for (int ni = 0; ni < 4; ++ni)
        acc[mi][ni] =
            __builtin_amdgcn_mfma_f32_16x16x32_bf16(af[mi], bfr[ni], acc[mi][ni], 0, 0, 0);
    __syncthreads();
  }

  // epilogue: per-wave LDS transpose, then coalesced 16B global stores
  const int h = (bn + n0) >> 6;                 // wave's 64 features = exactly one head
  unsigned short* OTw = &OT[w][0];
  if (wsel != 2) {
    // OT[row=s_local][col=e]
#pragma unroll
    for (int mi = 0; mi < 4; ++mi)
#pragma unroll
      for (int ni = 0; ni < 4; ++ni)
#pragma unroll
        for (int j = 0; j < 4; ++j)
          OTw[(mi * 16 + (lane >> 4) * 4 + j) * 72 + ni * 16 + (lane & 15)] =
              f2bf(acc[mi][ni][j]);
  } else {
    // OT[row=e][col=s_local]  (transposed store, 4 consecutive s pack to 8B)
#pragma unroll
    for (int mi = 0; mi < 4; ++mi)
#pragma unroll
      for (int ni = 0; ni < 4; ++ni) {
        us4 pk;
#pragma unroll
        for (int j = 0; j < 4; ++j) pk[j] = f2bf(acc[mi][ni][j]);
        *(us4*)&OTw[(ni * 16 + (lane & 15)) * 72 + mi * 16 + (lane >> 4) * 4] = pk;
      }
  }
  unsigned short* gout = (wsel == 0) ? qb : ((wsel == 1) ? kb : vt);
#pragma unroll
  for (int pass = 0; pass < 8; ++pass) {
    const int row = pass * 8 + (lane >> 3);
    bf16x8 vrow = *(const bf16x8*)&OTw[row * 72 + (lane & 7) * 8];
    size_t dst;
    if (wsel != 2)
      dst = ((size_t)(b * HH + h) * SS + (size_t)(bm + m0 + row)) * DHH + (lane & 7) * 8;
    else
      dst = ((size_t)(b * HH + h) * DHH + (size_t)row) * SS + (bm + m0) + (lane & 7) * 8;
    *(bf16x8*)&gout[dst] = vrow;
  }
}

// ---------------- Kernel C: fused attention (no online softmax needed: tanh bounds) ---
// grid: (16 q-tiles, 128 bh). 4 waves x 16 q-rows. K/V fragments straight from L2.
__global__ __launch_bounds__(256) void attn_kernel(
    const unsigned short* __restrict__ qb,
    const unsigned short* __restrict__ kb,
    const unsigned short* __restrict__ vt,
    const float* __restrict__ mask,
    float* __restrict__ out) {
  const int qt = blockIdx.x;
  const int bh = blockIdx.y;
  const int b = bh >> 3;
  const int h = bh & 7;
  const int tid = threadIdx.x;
  const int w = tid >> 6;
  const int lane = tid & 63;

  __shared__ float mask_s[SS];
  __shared__ unsigned short P_s[4][16 * 72];   // per-wave P relayout buffer (padded)

  *(float4v*)&mask_s[tid * 4] = *(const float4v*)&mask[b * SS + tid * 4];
  __syncthreads();

  const int q0 = qt * 64 + w * 16;
  const size_t base_qk = (size_t)bh * SS * DHH;
  const int pcol = lane & 15;
  const int prow = (lane >> 4) * 4;

  const unsigned short* qp =
      qb + base_qk + (size_t)(q0 + pcol) * DHH + (lane >> 4) * 8;
  const bf16x8 aq0 = *(const bf16x8*)qp;
  const bf16x8 aq1 = *(const bf16x8*)(qp + 32);

  f32x4 accO[4];
#pragma unroll
  for (int i = 0; i < 4; ++i) accO[i] = (f32x4){0.f, 0.f, 0.f, 0.f};
  float rs[4] = {0.f, 0.f, 0.f, 0.f};

  unsigned short* Pw = &P_s[w][0];

  for (int kt = 0; kt < 16; ++kt) {
    const int k0 = kt * 64;
    f32x4 sc[4];
#pragma unroll
    for (int ns = 0; ns < 4; ++ns) sc[ns] = (f32x4){0.f, 0.f, 0.f, 0.f};
#pragma unroll
    for (int ns = 0; ns < 4; ++ns) {
      const unsigned short* kp =
          kb + base_qk + (size_t)(k0 + ns * 16 + pcol) * DHH + (lane >> 4) * 8;
      bf16x8 bk0 = *(const bf16x8*)kp;
      bf16x8 bk1 = *(const bf16x8*)(kp + 32);
      sc[ns] = __builtin_amdgcn_mfma_f32_16x16x32_bf16(aq0, bk0, sc[ns], 0, 0, 0);
      sc[ns] = __builtin_amdgcn_mfma_f32_16x16x32_bf16(aq1, bk1, sc[ns], 0, 0, 0);
    }
    // p = mask * exp(tanh(s/8)); accumulate rowsums; stash bf16 P for the PV relayout
#pragma unroll
    for (int ns = 0; ns < 4; ++ns) {
      const float mval = mask_s[k0 + ns * 16 + pcol];
#pragma unroll
      for (int j = 0; j < 4; ++j) {
        float e2 = __builtin_amdgcn_exp2f(sc[ns][j] * 0.36067376022f);  // e^{2x}, x=s/8
        float t = 1.f - 2.f * __builtin_amdgcn_rcpf(1.f + e2);          // tanh(s/8)
        float p = mval * __builtin_amdgcn_exp2f(t * 1.44269504089f);    // e^{tanh}
        rs[j] += p;
        Pw[(prow + j) * 72 + ns * 16 + pcol] = f2bf(p);
      }
    }
    // PV: A = P[q][key] from LDS, B = vT[e][key] from global (16B/lane, L2-resident)
#pragma unroll
    for (int c = 0; c < 2; ++c) {
      bf16x8 ap = *(const bf16x8*)&Pw[pcol * 72 + c * 32 + (lane >> 4) * 8];
#pragma unroll
      for (int n2 = 0; n2 < 4; ++n2) {
        const unsigned short* vp = vt + ((size_t)bh * DHH + n2 * 16 + pcol) * SS + k0 +
                                   c * 32 + (lane >> 4) * 8;
        bf16x8 bv = *(const bf16x8*)vp;
        accO[n2] = __builtin_amdgcn_mfma_f32_16x16x32_bf16(ap, bv, accO[n2], 0, 0, 0);
      }
    }
  }

  // reduce rowsums across the 16 key-lanes of each row group
#pragma unroll
  for (int j = 0; j < 4; ++j) {
    float v = rs[j];
    v += __shfl_xor(v, 1);
    v += __shfl_xor(v, 2);
    v += __shfl_xor(v, 4);
    v += __shfl_xor(v, 8);
    rs[j] = v;
  }

#pragma unroll
  for (int n2 = 0; n2 < 4; ++n2)
#pragma unroll
    for (int j = 0; j < 4; ++j) {
      const int srow = q0 + prow + j;
      out[((size_t)srow * BB + b) * DD + h * DHH + n2 * 16 + pcol] = accO[n2][j] / rs[j];
    }
}

extern "C" void kernel_launch(void* const* d_in, const int* in_sizes, int n_in,
                              void* d_out, int out_size, void* d_ws, size_t ws_size,
                              hipStream_t stream) {
  const float* x = (const float*)d_in[0];
  const float* mask = (const float*)d_in[1];
  const float* wq = (const float*)d_in[2];
  const float* wk = (const float*)d_in[3];
  const float* wv = (const float*)d_in[4];
  float* out = (float*)d_out;

  char* ws = (char*)d_ws;
  unsigned short* xb = (unsigned short*)(ws);                         // 16 MB
  unsigned short* wb = (unsigned short*)(ws + (16ull << 20));         // 1.5 MB (pad 2)
  unsigned short* qb = (unsigned short*)(ws + (18ull << 20));         // 16 MB
  unsigned short* kb = (unsigned short*)(ws + (34ull << 20));         // 16 MB
  unsigned short* vt = (unsigned short*)(ws + (50ull << 20));         // 16 MB -> 66 MB

  cvt_kernel<<<dim3(8960), 256, 0, stream>>>(x, wq, wk, wv, xb, wb);
  proj_kernel<<<dim3(8, 4, 48), 256, 0, stream>>>(xb, wb, qb, kb, vt);
  attn_kernel<<<dim3(16, 128), 256, 0, stream>>>(qb, kb, vt, mask, out);
}

// Round 2
// 124.517 us; speedup vs baseline: 2.4408x; 2.4408x over previous
//
#include <hip/hip_runtime.h>
#include <stdint.h>
#include <stddef.h>

#define SS 1024
#define BB 16
#define DD 512
#define HH 8
#define DHH 64

typedef __attribute__((ext_vector_type(8))) short bf16x8;
typedef __attribute__((ext_vector_type(4))) float f32x4;
typedef __attribute__((ext_vector_type(4))) float float4v;
typedef __attribute__((ext_vector_type(2))) float float2v;
typedef __attribute__((ext_vector_type(4))) unsigned short us4;

__device__ __forceinline__ unsigned short f2bf(float f) {
  union { float f; unsigned int u; } v; v.f = f;
  unsigned int x = v.u;
  return (unsigned short)((x + 0x7FFFu + ((x >> 16) & 1u)) >> 16);
}

// async global->LDS, 16B per lane; LDS dest is wave-uniform base (+lane*16 implicit)
#define GLDS16(dst, src)                                                                  \
  __builtin_amdgcn_global_load_lds(                                                      \
      (const __attribute__((address_space(1))) unsigned int*)(const void*)(src),         \
      (__attribute__((address_space(3))) unsigned int*)(void*)(dst), 16, 0, 0)

// ---------------- Kernel A: f32 -> bf16 conversion (x and the 3 weight stacks) --------
__global__ void cvt_kernel(const float* __restrict__ x,
                           const float* __restrict__ wq,
                           const float* __restrict__ wk,
                           const float* __restrict__ wv,
                           unsigned short* __restrict__ xb,
                           unsigned short* __restrict__ wb) {
  const int i = blockIdx.x * 256 + threadIdx.x;   // one float4 per thread
  const int n_x4 = (SS * BB * DD) / 4;            // 2,097,152
  if (i < n_x4) {
    float4v v = ((const float4v*)x)[i];
    us4 o;
    o[0] = f2bf(v[0]); o[1] = f2bf(v[1]); o[2] = f2bf(v[2]); o[3] = f2bf(v[3]);
    ((us4*)xb)[i] = o;
  } else {
    const int j = i - n_x4;            // 0..196607
    const int sel = j >> 16;           // which weight (65536 float4 each)
    const int off4 = j & 65535;
    const float* wsrc = (sel == 0) ? wq : ((sel == 1) ? wk : wv);
    float4v v = ((const float4v*)wsrc)[off4];
    us4 o;
    o[0] = f2bf(v[0]); o[1] = f2bf(v[1]); o[2] = f2bf(v[2]); o[3] = f2bf(v[3]);
    ((us4*)wb)[(sel << 16) + off4] = o;
  }
}

// ---------------- Kernel B: projection GEMM  Y[s,f] = sum_d x[s,b,d] * w[f,d] ---------
// grid: (8 M-tiles, 4 N-tiles, 48 = b*3+wsel). 128x128 tile, BK=32, 4 waves of 64x64.
// Outputs: wsel 0/1 -> q/k as [bh][s][e] bf16 ; wsel 2 -> vT as [bh][e][s] bf16.
__global__ __launch_bounds__(256) void proj_kernel(
    const unsigned short* __restrict__ xb,
    const unsigned short* __restrict__ wb,
    unsigned short* __restrict__ qb,
    unsigned short* __restrict__ kb,
    unsigned short* __restrict__ vt) {
  const int bm = blockIdx.x * 128;
  const int bn = blockIdx.y * 128;
  const int b = blockIdx.z / 3;
  const int wsel = blockIdx.z % 3;

  __shared__ unsigned short At[128 * 32];
  __shared__ unsigned short Bt[128 * 32];
  __shared__ unsigned short OT[4][64 * 72];   // per-wave 64x64 transpose pad +8

  const int tid = threadIdx.x;
  const int w = tid >> 6;
  const int lane = tid & 63;

  const unsigned short* wptr = wb + wsel * (512 * DD);

  f32x4 acc[4][4];
#pragma unroll
  for (int mi = 0; mi < 4; ++mi)
#pragma unroll
    for (int ni = 0; ni < 4; ++ni) acc[mi][ni] = (f32x4){0.f, 0.f, 0.f, 0.f};

  const int m0 = (w & 1) * 64;
  const int n0 = (w >> 1) * 64;

  for (int kt = 0; kt < 16; ++kt) {
#pragma unroll
    for (int i = 0; i < 2; ++i) {
      const int idx8 = i * 256 + tid;        // 0..511 : r = idx8/4, c8 = idx8%4
      const int r = idx8 >> 2;
      const int c8 = idx8 & 3;
      GLDS16(&At[(i * 256 + w * 64) * 8],
             xb + (size_t)(bm + r) * (BB * DD) + b * DD + kt * 32 + c8 * 8);
      GLDS16(&Bt[(i * 256 + w * 64) * 8],
             wptr + (size_t)(bn + r) * DD + kt * 32 + c8 * 8);
    }
    __syncthreads();
    bf16x8 af[4], bfr[4];
#pragma unroll
    for (int mi = 0; mi < 4; ++mi)
      af[mi] = *(const bf16x8*)&At[(m0 + mi * 16 + (lane & 15)) * 32 + (lane >> 4) * 8];
#pragma unroll
    for (int ni = 0; ni < 4; ++ni)
      bfr[ni] = *(const bf16x8*)&Bt[(n0 + ni * 16 + (lane & 15)) * 32 + (lane >> 4) * 8];
#pragma unroll
    for (int mi = 0; mi < 4; ++mi)
#pragma unroll
      for (int ni = 0; ni < 4; ++ni)
        acc[mi][ni] =
            __builtin_amdgcn_mfma_f32_16x16x32_bf16(af[mi], bfr[ni], acc[mi][ni], 0, 0, 0);
    __syncthreads();
  }

  // epilogue: per-wave LDS transpose, then coalesced 16B global stores
  const int h = (bn + n0) >> 6;                 // wave's 64 features = exactly one head
  unsigned short* OTw = &OT[w][0];
  if (wsel != 2) {
    // OT[row=s_local][col=e]
#pragma unroll
    for (int mi = 0; mi < 4; ++mi)
#pragma unroll
      for (int ni = 0; ni < 4; ++ni)
#pragma unroll
        for (int j = 0; j < 4; ++j)
          OTw[(mi * 16 + (lane >> 4) * 4 + j) * 72 + ni * 16 + (lane & 15)] =
              f2bf(acc[mi][ni][j]);
  } else {
    // OT[row=e][col=s_local]  (transposed store, 4 consecutive s pack to 8B)
#pragma unroll
    for (int mi = 0; mi < 4; ++mi)
#pragma unroll
      for (int ni = 0; ni < 4; ++ni) {
        us4 pk;
#pragma unroll
        for (int j = 0; j < 4; ++j) pk[j] = f2bf(acc[mi][ni][j]);
        *(us4*)&OTw[(ni * 16 + (lane & 15)) * 72 + mi * 16 + (lane >> 4) * 4] = pk;
      }
  }
  unsigned short* gout = (wsel == 0) ? qb : ((wsel == 1) ? kb : vt);
#pragma unroll
  for (int pass = 0; pass < 8; ++pass) {
    const int row = pass * 8 + (lane >> 3);
    bf16x8 vrow = *(const bf16x8*)&OTw[row * 72 + (lane & 7) * 8];
    size_t dst;
    if (wsel != 2)
      dst = ((size_t)(b * HH + h) * SS + (size_t)(bm + m0 + row)) * DHH + (lane & 7) * 8;
    else
      dst = ((size_t)(b * HH + h) * DHH + (size_t)row) * SS + (bm + m0) + (lane & 7) * 8;
    *(bf16x8*)&gout[dst] = vrow;
  }
}

// ---------------- Kernel C: fused attention, v2 ---------------------------------------
// 8 waves x 16 q-rows = 128 q-rows/block; K/V LDS-staged, double-buffered (2-phase),
// XOR-swizzled (T2, both-sides: pre-swizzled global src + swizzled ds_read);
// XCD-aware block mapping (T1, bijective).
__global__ __launch_bounds__(512, 3) void attn_kernel(
    const unsigned short* __restrict__ qb,
    const unsigned short* __restrict__ kb,
    const unsigned short* __restrict__ vt,
    const float* __restrict__ mask,
    float* __restrict__ out) {
  // bijective XCD decode: 1024 blocks = 8 XCDs x (16 bh x 8 qt)
  const int id = blockIdx.x;
  const int xcd = id & 7;
  const int slot = id >> 3;
  const int bh = xcd * 16 + (slot >> 3);
  const int qt = slot & 7;
  const int b = bh >> 3;
  const int h = bh & 7;
  const int tid = threadIdx.x;
  const int w = tid >> 6;
  const int lane = tid & 63;
  const int pcol = lane & 15;
  const int hi = lane >> 4;

  __shared__ float mask_s[SS];                 // pre-scaled by e
  __shared__ unsigned short Ks[2][64 * 64];    // [key][dh], 128B rows, XOR-swizzled
  __shared__ unsigned short Vs[2][64 * 64];    // [e][key],  128B rows, XOR-swizzled
  __shared__ unsigned short P_s[8][16 * 72];   // per-wave P relayout buffer (padded)

  {
    float2v mv = *(const float2v*)&mask[b * SS + tid * 2];
    mask_s[tid * 2] = mv[0] * 2.71828182845904523f;
    mask_s[tid * 2 + 1] = mv[1] * 2.71828182845904523f;
  }

  const size_t base_qk = (size_t)bh * SS * DHH;
  const int q0 = qt * 128 + w * 16;

  const unsigned short* qp = qb + base_qk + (size_t)(q0 + pcol) * DHH + hi * 8;
  const bf16x8 aq0 = *(const bf16x8*)qp;
  const bf16x8 aq1 = *(const bf16x8*)(qp + 32);

  // staging: wave w fills rows [8w, 8w+8) of each 64x(128B) tile; 1 instr K + 1 instr V.
  // LDS dest is lane-linear; source col is inverse-swizzled so reads can swizzle.
  const int srow = w * 8 + (lane >> 3);                       // tile-local row
  const int sxb = ((lane & 7) << 4) ^ ((srow & 7) << 4);      // swizzled byte col in row
  const unsigned short* ksrc = kb + base_qk + (size_t)srow * DHH + (sxb >> 1);
  const unsigned short* vsrc = vt + (size_t)bh * DHH * SS + (size_t)srow * SS + (sxb >> 1);

#define STAGE(bb, kt2)                                                    \
  do {                                                                    \
    GLDS16(&Ks[bb][w * 512], ksrc + (size_t)(kt2) * (64 * DHH));          \
    GLDS16(&Vs[bb][w * 512], vsrc + (size_t)(kt2) * 64);                  \
  } while (0)

  STAGE(0, 0);

  f32x4 accO[4];
#pragma unroll
  for (int i = 0; i < 4; ++i) accO[i] = (f32x4){0.f, 0.f, 0.f, 0.f};
  float rs[4] = {0.f, 0.f, 0.f, 0.f};
  unsigned short* Pw = &P_s[w][0];
  const int prow = hi * 4;

  __syncthreads();   // drains vmcnt: tile 0 resident; mask_s visible

  int buf = 0;
  for (int kt = 0; kt < 16; ++kt) {
    if (kt < 15) STAGE(buf ^ 1, kt + 1);     // prefetch next tile (in flight all phase)

    const char* Kb = (const char*)&Ks[buf][0];
    const char* Vb = (const char*)&Vs[buf][0];
    const int k0 = kt * 64;

    f32x4 sc[4];
#pragma unroll
    for (int ns = 0; ns < 4; ++ns) sc[ns] = (f32x4){0.f, 0.f, 0.f, 0.f};
#pragma unroll
    for (int ns = 0; ns < 4; ++ns) {
      const int row = ns * 16 + pcol;
      const int sw = (row & 7) << 4;
      bf16x8 bk0 = *(const bf16x8*)(Kb + row * 128 + ((hi * 16) ^ sw));
      bf16x8 bk1 = *(const bf16x8*)(Kb + row * 128 + ((64 + hi * 16) ^ sw));
      sc[ns] = __builtin_amdgcn_mfma_f32_16x16x32_bf16(aq0, bk0, sc[ns], 0, 0, 0);
      sc[ns] = __builtin_amdgcn_mfma_f32_16x16x32_bf16(aq1, bk1, sc[ns], 0, 0, 0);
    }

    // p = maskE * exp2(-2*log2e * rcp(1 + e^{2x})), x = s/8  (== mask * e^{tanh(s/8)})
#pragma unroll
    for (int ns = 0; ns < 4; ++ns) {
      const float me = mask_s[k0 + ns * 16 + pcol];
#pragma unroll
      for (int j = 0; j < 4; ++j) {
        float u = __builtin_amdgcn_exp2f(sc[ns][j] * 0.36067376022f);
        float r = __builtin_amdgcn_rcpf(1.f + u);
        float p = me * __builtin_amdgcn_exp2f(-2.88539008178f * r);
        rs[j] += p;
        union { float f; unsigned int u; } pv_;
        pv_.f = p;
        Pw[(prow + j) * 72 + ns * 16 + pcol] = (unsigned short)(pv_.u >> 16);
      }
    }

    // PV: A = P[q][key] from LDS, B = vT[e][key] from swizzled LDS
#pragma unroll
    for (int c = 0; c < 2; ++c) {
      bf16x8 ap = *(const bf16x8*)&Pw[pcol * 72 + c * 32 + hi * 8];
#pragma unroll
      for (int n2 = 0; n2 < 4; ++n2) {
        const int row = n2 * 16 + pcol;
        const int sw = (row & 7) << 4;
        bf16x8 bv = *(const bf16x8*)(Vb + row * 128 + ((c * 64 + hi * 16) ^ sw));
        accO[n2] = __builtin_amdgcn_mfma_f32_16x16x32_bf16(ap, bv, accO[n2], 0, 0, 0);
      }
    }

    __syncthreads();   // drains vmcnt (next tile landed) + protects buffer flip
    buf ^= 1;
  }
#undef STAGE

  // reduce rowsums across the 16 key-lanes of each row group
#pragma unroll
  for (int j = 0; j < 4; ++j) {
    float v = rs[j];
    v += __shfl_xor(v, 1);
    v += __shfl_xor(v, 2);
    v += __shfl_xor(v, 4);
    v += __shfl_xor(v, 8);
    rs[j] = v;
  }

#pragma unroll
  for (int n2 = 0; n2 < 4; ++n2)
#pragma unroll
    for (int j = 0; j < 4; ++j) {
      const int srow_o = q0 + prow + j;
      out[((size_t)srow_o * BB + b) * DD + h * DHH + n2 * 16 + pcol] = accO[n2][j] / rs[j];
    }
}

extern "C" void kernel_launch(void* const* d_in, const int* in_sizes, int n_in,
                              void* d_out, int out_size, void* d_ws, size_t ws_size,
                              hipStream_t stream) {
  const float* x = (const float*)d_in[0];
  const float* mask = (const float*)d_in[1];
  const float* wq = (const float*)d_in[2];
  const float* wk = (const float*)d_in[3];
  const float* wv = (const float*)d_in[4];
  float* out = (float*)d_out;

  char* ws = (char*)d_ws;
  unsigned short* xb = (unsigned short*)(ws);                         // 16 MB
  unsigned short* wb = (unsigned short*)(ws + (16ull << 20));         // 1.5 MB (pad 2)
  unsigned short* qb = (unsigned short*)(ws + (18ull << 20));         // 16 MB
  unsigned short* kb = (unsigned short*)(ws + (34ull << 20));         // 16 MB
  unsigned short* vt = (unsigned short*)(ws + (50ull << 20));         // 16 MB -> 66 MB

  cvt_kernel<<<dim3(8960), 256, 0, stream>>>(x, wq, wk, wv, xb, wb);
  proj_kernel<<<dim3(8, 4, 48), 256, 0, stream>>>(xb, wb, qb, kb, vt);
  attn_kernel<<<dim3(1024), 512, 0, stream>>>(qb, kb, vt, mask, out);
}

// Round 3
// 118.821 us; speedup vs baseline: 2.5578x; 1.0479x over previous
//
#include <hip/hip_runtime.h>
#include <stdint.h>
#include <stddef.h>

#define SS 1024
#define BB 16
#define DD 512
#define HH 8
#define DHH 64

typedef __attribute__((ext_vector_type(8))) short bf16x8;
typedef __attribute__((ext_vector_type(4))) float f32x4;
typedef __attribute__((ext_vector_type(4))) float float4v;
typedef __attribute__((ext_vector_type(2))) float float2v;
typedef __attribute__((ext_vector_type(4))) unsigned short us4;
typedef __attribute__((ext_vector_type(2))) unsigned int uint2v;

__device__ __forceinline__ unsigned short f2bf(float f) {
  union { float f; unsigned int u; } v; v.f = f;
  unsigned int x = v.u;
  return (unsigned short)((x + 0x7FFFu + ((x >> 16) & 1u)) >> 16);
}

// async global->LDS, 16B per lane; LDS dest is wave-uniform base (+lane*16 implicit)
#define GLDS16(dst, src)                                                                  \
  __builtin_amdgcn_global_load_lds(                                                      \
      (const __attribute__((address_space(1))) unsigned int*)(const void*)(src),         \
      (__attribute__((address_space(3))) unsigned int*)(void*)(dst), 16, 0, 0)

// ---------------- Kernel A: f32 -> bf16 conversion (x and the 3 weight stacks) --------
__global__ void cvt_kernel(const float* __restrict__ x,
                           const float* __restrict__ wq,
                           const float* __restrict__ wk,
                           const float* __restrict__ wv,
                           unsigned short* __restrict__ xb,
                           unsigned short* __restrict__ wb) {
  const int i = blockIdx.x * 256 + threadIdx.x;   // one float4 per thread
  const int n_x4 = (SS * BB * DD) / 4;            // 2,097,152
  if (i < n_x4) {
    float4v v = ((const float4v*)x)[i];
    us4 o;
    o[0] = f2bf(v[0]); o[1] = f2bf(v[1]); o[2] = f2bf(v[2]); o[3] = f2bf(v[3]);
    ((us4*)xb)[i] = o;
  } else {
    const int j = i - n_x4;            // 0..196607
    const int sel = j >> 16;           // which weight (65536 float4 each)
    const int off4 = j & 65535;
    const float* wsrc = (sel == 0) ? wq : ((sel == 1) ? wk : wv);
    float4v v = ((const float4v*)wsrc)[off4];
    us4 o;
    o[0] = f2bf(v[0]); o[1] = f2bf(v[1]); o[2] = f2bf(v[2]); o[3] = f2bf(v[3]);
    ((us4*)wb)[(sel << 16) + off4] = o;
  }
}

// ---------------- Kernel B: projection GEMM  Y[s,f] = sum_d x[s,b,d] * w[f,d] ---------
// grid: (8 M-tiles, 4 N-tiles, 48 = b*3+wsel). 128x128 tile, BK=32, 4 waves of 64x64.
// Outputs: wsel 0/1 -> q/k as [bh][s][e] bf16 ; wsel 2 -> vT as [bh][e][s] bf16.
__global__ __launch_bounds__(256) void proj_kernel(
    const unsigned short* __restrict__ xb,
    const unsigned short* __restrict__ wb,
    unsigned short* __restrict__ qb,
    unsigned short* __restrict__ kb,
    unsigned short* __restrict__ vt) {
  const int bm = blockIdx.x * 128;
  const int bn = blockIdx.y * 128;
  const int b = blockIdx.z / 3;
  const int wsel = blockIdx.z % 3;

  __shared__ unsigned short At[128 * 32];
  __shared__ unsigned short Bt[128 * 32];
  __shared__ unsigned short OT[4][64 * 72];   // per-wave 64x64 transpose pad +8

  const int tid = threadIdx.x;
  const int w = tid >> 6;
  const int lane = tid & 63;

  const unsigned short* wptr = wb + wsel * (512 * DD);

  f32x4 acc[4][4];
#pragma unroll
  for (int mi = 0; mi < 4; ++mi)
#pragma unroll
    for (int ni = 0; ni < 4; ++ni) acc[mi][ni] = (f32x4){0.f, 0.f, 0.f, 0.f};

  const int m0 = (w & 1) * 64;
  const int n0 = (w >> 1) * 64;

  for (int kt = 0; kt < 16; ++kt) {
#pragma unroll
    for (int i = 0; i < 2; ++i) {
      const int idx8 = i * 256 + tid;        // 0..511 : r = idx8/4, c8 = idx8%4
      const int r = idx8 >> 2;
      const int c8 = idx8 & 3;
      GLDS16(&At[(i * 256 + w * 64) * 8],
             xb + (size_t)(bm + r) * (BB * DD) + b * DD + kt * 32 + c8 * 8);
      GLDS16(&Bt[(i * 256 + w * 64) * 8],
             wptr + (size_t)(bn + r) * DD + kt * 32 + c8 * 8);
    }
    __syncthreads();
    bf16x8 af[4], bfr[4];
#pragma unroll
    for (int mi = 0; mi < 4; ++mi)
      af[mi] = *(const bf16x8*)&At[(m0 + mi * 16 + (lane & 15)) * 32 + (lane >> 4) * 8];
#pragma unroll
    for (int ni = 0; ni < 4; ++ni)
      bfr[ni] = *(const bf16x8*)&Bt[(n0 + ni * 16 + (lane & 15)) * 32 + (lane >> 4) * 8];
#pragma unroll
    for (int mi = 0; mi < 4; ++mi)
#pragma unroll
      for (int ni = 0; ni < 4; ++ni)
        acc[mi][ni] =
            __builtin_amdgcn_mfma_f32_16x16x32_bf16(af[mi], bfr[ni], acc[mi][ni], 0, 0, 0);
    __syncthreads();
  }

  // epilogue: per-wave LDS transpose, then coalesced 16B global stores
  const int h = (bn + n0) >> 6;                 // wave's 64 features = exactly one head
  unsigned short* OTw = &OT[w][0];
  if (wsel != 2) {
    // OT[row=s_local][col=e]
#pragma unroll
    for (int mi = 0; mi < 4; ++mi)
#pragma unroll
      for (int ni = 0; ni < 4; ++ni)
#pragma unroll
        for (int j = 0; j < 4; ++j)
          OTw[(mi * 16 + (lane >> 4) * 4 + j) * 72 + ni * 16 + (lane & 15)] =
              f2bf(acc[mi][ni][j]);
  } else {
    // OT[row=e][col=s_local]  (transposed store, 4 consecutive s pack to 8B)
#pragma unroll
    for (int mi = 0; mi < 4; ++mi)
#pragma unroll
      for (int ni = 0; ni < 4; ++ni) {
        us4 pk;
#pragma unroll
        for (int j = 0; j < 4; ++j) pk[j] = f2bf(acc[mi][ni][j]);
        *(us4*)&OTw[(ni * 16 + (lane & 15)) * 72 + mi * 16 + (lane >> 4) * 4] = pk;
      }
  }
  unsigned short* gout = (wsel == 0) ? qb : ((wsel == 1) ? kb : vt);
#pragma unroll
  for (int pass = 0; pass < 8; ++pass) {
    const int row = pass * 8 + (lane >> 3);
    bf16x8 vrow = *(const bf16x8*)&OTw[row * 72 + (lane & 7) * 8];
    size_t dst;
    if (wsel != 2)
      dst = ((size_t)(b * HH + h) * SS + (size_t)(bm + m0 + row)) * DHH + (lane & 7) * 8;
    else
      dst = ((size_t)(b * HH + h) * DHH + (size_t)row) * SS + (bm + m0) + (lane & 7) * 8;
    *(bf16x8*)&gout[dst] = vrow;
  }
}

// ---------------- Kernel C: fused attention, v3 ---------------------------------------
// Swapped QK^T (scores land key-major) -> P packed in-register (v_perm) + 4x ds_write_b64
// into an XOR-swizzled per-wave P tile. LDS 52KB -> 3 blocks/CU.
__global__ __launch_bounds__(512, 6) void attn_kernel(
    const unsigned short* __restrict__ qb,
    const unsigned short* __restrict__ kb,
    const unsigned short* __restrict__ vt,
    const float* __restrict__ mask,
    float* __restrict__ out) {
  // bijective XCD decode: 1024 blocks = 8 XCDs x (16 bh x 8 qt)
  const int id = blockIdx.x;
  const int xcd = id & 7;
  const int slot = id >> 3;
  const int bh = xcd * 16 + (slot >> 3);
  const int qt = slot & 7;
  const int b = bh >> 3;
  const int h = bh & 7;
  const int tid = threadIdx.x;
  const int w = tid >> 6;
  const int lane = tid & 63;
  const int pcol = lane & 15;
  const int hi = lane >> 4;

  __shared__ float mask_s[SS];                 // raw 0/1 (constant factors cancel)
  __shared__ unsigned short Ks[2][64 * 64];    // [key][dh], 128B rows, XOR-swizzled
  __shared__ unsigned short Vs[2][64 * 64];    // [e][key],  128B rows, XOR-swizzled
  __shared__ unsigned short P_s[8][16 * 64];   // per-wave P [q][key], XOR-swizzled

  {
    float2v mv = *(const float2v*)&mask[b * SS + tid * 2];
    mask_s[tid * 2] = mv[0];
    mask_s[tid * 2 + 1] = mv[1];
  }

  const size_t base_qk = (size_t)bh * SS * DHH;
  const int q0 = qt * 128 + w * 16;

  const unsigned short* qp = qb + base_qk + (size_t)(q0 + pcol) * DHH + hi * 8;
  const bf16x8 aq0 = *(const bf16x8*)qp;
  const bf16x8 aq1 = *(const bf16x8*)(qp + 32);

  // staging: wave w fills rows [8w, 8w+8) of each 64x(128B) tile; 1 instr K + 1 instr V.
  const int srow = w * 8 + (lane >> 3);                       // tile-local row
  const int sxb = ((lane & 7) << 4) ^ ((srow & 7) << 4);      // swizzled byte col in row
  const unsigned short* ksrc = kb + base_qk + (size_t)srow * DHH + (sxb >> 1);
  const unsigned short* vsrc = vt + (size_t)bh * DHH * SS + (size_t)srow * SS + (sxb >> 1);

#define STAGE(bb, kt2)                                                    \
  do {                                                                    \
    GLDS16(&Ks[bb][w * 512], ksrc + (size_t)(kt2) * (64 * DHH));          \
    GLDS16(&Vs[bb][w * 512], vsrc + (size_t)(kt2) * 64);                  \
  } while (0)

  STAGE(0, 0);

  f32x4 accO[4];
#pragma unroll
  for (int i = 0; i < 4; ++i) accO[i] = (f32x4){0.f, 0.f, 0.f, 0.f};
  float rs = 0.f;
  char* PwB = (char*)&P_s[w][0];
  const int pswz = (pcol & 7) << 4;

  __syncthreads();   // drains vmcnt: tile 0 resident; mask_s visible

#define BODY(BUF, KT)                                                                    \
  do {                                                                                   \
    if ((KT) < 15) STAGE((BUF) ^ 1, (KT) + 1);                                           \
    const char* Kb = (const char*)&Ks[BUF][0];                                           \
    const char* Vb = (const char*)&Vs[BUF][0];                                           \
    const int k0 = (KT) * 64;                                                            \
    f32x4 sc[4];                                                                         \
    _Pragma("unroll") for (int ns = 0; ns < 4; ++ns) {                                   \
      sc[ns] = (f32x4){0.f, 0.f, 0.f, 0.f};                                              \
      const int row = ns * 16 + pcol;                                                    \
      const int sw = (row & 7) << 4;                                                     \
      bf16x8 bk0 = *(const bf16x8*)(Kb + row * 128 + ((hi * 16) ^ sw));                  \
      bf16x8 bk1 = *(const bf16x8*)(Kb + row * 128 + ((64 + hi * 16) ^ sw));             \
      sc[ns] = __builtin_amdgcn_mfma_f32_16x16x32_bf16(bk0, aq0, sc[ns], 0, 0, 0);       \
      sc[ns] = __builtin_amdgcn_mfma_f32_16x16x32_bf16(bk1, aq1, sc[ns], 0, 0, 0);       \
    }                                                                                    \
    _Pragma("unroll") for (int ns = 0; ns < 4; ++ns) {                                   \
      float4v mv = *(const float4v*)&mask_s[k0 + ns * 16 + hi * 4];                      \
      unsigned int pu[4];                                                                \
      _Pragma("unroll") for (int j = 0; j < 4; ++j) {                                    \
        float u = __builtin_amdgcn_exp2f(sc[ns][j] * 0.36067376022f);                    \
        float r = __builtin_amdgcn_rcpf(1.f + u);                                        \
        float p = mv[j] * __builtin_amdgcn_exp2f(-2.88539008178f * r);                   \
        rs += p;                                                                         \
        union { float f; unsigned int u; } cv;                                           \
        cv.f = p;                                                                        \
        pu[j] = cv.u;                                                                    \
      }                                                                                  \
      uint2v pk;                                                                         \
      pk[0] = __builtin_amdgcn_perm(pu[1], pu[0], 0x07060302u);                          \
      pk[1] = __builtin_amdgcn_perm(pu[3], pu[2], 0x07060302u);                          \
      *(uint2v*)(PwB + pcol * 128 + ((ns * 32 + hi * 8) ^ pswz)) = pk;                   \
    }                                                                                    \
    _Pragma("unroll") for (int c = 0; c < 2; ++c) {                                      \
      bf16x8 ap = *(const bf16x8*)(PwB + pcol * 128 + ((c * 64 + hi * 16) ^ pswz));      \
      _Pragma("unroll") for (int n2 = 0; n2 < 4; ++n2) {                                 \
        const int row = n2 * 16 + pcol;                                                  \
        const int sw = (row & 7) << 4;                                                   \
        bf16x8 bv = *(const bf16x8*)(Vb + row * 128 + ((c * 64 + hi * 16) ^ sw));        \
        accO[n2] = __builtin_amdgcn_mfma_f32_16x16x32_bf16(ap, bv, accO[n2], 0, 0, 0);   \
      }                                                                                  \
    }                                                                                    \
    __syncthreads();                                                                     \
  } while (0)

  for (int kt = 0; kt < 16; kt += 2) {
    BODY(0, kt);
    BODY(1, kt + 1);
  }
#undef BODY
#undef STAGE

  // rowsum: lane holds partial over its 16 keys/kt; reduce across hi-groups
  rs += __shfl_xor(rs, 16);
  rs += __shfl_xor(rs, 32);

#pragma unroll
  for (int j = 0; j < 4; ++j) {
    const float rq = __shfl(rs, hi * 4 + j);       // lanes 0..15 hold column sums
    const float rinv = __builtin_amdgcn_rcpf(rq);
    const int srow_o = q0 + hi * 4 + j;
#pragma unroll
    for (int n2 = 0; n2 < 4; ++n2)
      out[((size_t)srow_o * BB + b) * DD + h * DHH + n2 * 16 + pcol] = accO[n2][j] * rinv;
  }
}

extern "C" void kernel_launch(void* const* d_in, const int* in_sizes, int n_in,
                              void* d_out, int out_size, void* d_ws, size_t ws_size,
                              hipStream_t stream) {
  const float* x = (const float*)d_in[0];
  const float* mask = (const float*)d_in[1];
  const float* wq = (const float*)d_in[2];
  const float* wk = (const float*)d_in[3];
  const float* wv = (const float*)d_in[4];
  float* out = (float*)d_out;

  char* ws = (char*)d_ws;
  unsigned short* xb = (unsigned short*)(ws);                         // 16 MB
  unsigned short* wb = (unsigned short*)(ws + (16ull << 20));         // 1.5 MB (pad 2)
  unsigned short* qb = (unsigned short*)(ws + (18ull << 20));         // 16 MB
  unsigned short* kb = (unsigned short*)(ws + (34ull << 20));         // 16 MB
  unsigned short* vt = (unsigned short*)(ws + (50ull << 20));         // 16 MB -> 66 MB

  cvt_kernel<<<dim3(8960), 256, 0, stream>>>(x, wq, wk, wv, xb, wb);
  proj_kernel<<<dim3(8, 4, 48), 256, 0, stream>>>(xb, wb, qb, kb, vt);
  attn_kernel<<<dim3(1024), 512, 0, stream>>>(qb, kb, vt, mask, out);
}

// Round 4
// 115.188 us; speedup vs baseline: 2.6384x; 1.0315x over previous
//
#include <hip/hip_runtime.h>
#include <stdint.h>
#include <stddef.h>

#define SS 1024
#define BB 16
#define DD 512
#define HH 8
#define DHH 64

typedef __attribute__((ext_vector_type(8))) short bf16x8;
typedef __attribute__((ext_vector_type(4))) float f32x4;
typedef __attribute__((ext_vector_type(16))) float f32x16;
typedef __attribute__((ext_vector_type(4))) float float4v;
typedef __attribute__((ext_vector_type(2))) float float2v;
typedef __attribute__((ext_vector_type(4))) unsigned short us4;

__device__ __forceinline__ unsigned short f2bf(float f) {
  union { float f; unsigned int u; } v; v.f = f;
  unsigned int x = v.u;
  return (unsigned short)((x + 0x7FFFu + ((x >> 16) & 1u)) >> 16);
}

// async global->LDS, 16B per lane; LDS dest is wave-uniform base (+lane*16 implicit)
#define GLDS16(dst, src)                                                                  \
  __builtin_amdgcn_global_load_lds(                                                      \
      (const __attribute__((address_space(1))) unsigned int*)(const void*)(src),         \
      (__attribute__((address_space(3))) unsigned int*)(void*)(dst), 16, 0, 0)

// ---------------- Kernel A: f32 -> bf16 conversion (x and the 3 weight stacks) --------
// wq is pre-scaled by 2/(8*ln2) so the attn softmax can use exp2(sc) directly.
__global__ void cvt_kernel(const float* __restrict__ x,
                           const float* __restrict__ wq,
                           const float* __restrict__ wk,
                           const float* __restrict__ wv,
                           unsigned short* __restrict__ xb,
                           unsigned short* __restrict__ wb) {
  const int i = blockIdx.x * 256 + threadIdx.x;   // one float4 per thread
  const int n_x4 = (SS * BB * DD) / 4;            // 2,097,152
  if (i < n_x4) {
    float4v v = ((const float4v*)x)[i];
    us4 o;
    o[0] = f2bf(v[0]); o[1] = f2bf(v[1]); o[2] = f2bf(v[2]); o[3] = f2bf(v[3]);
    ((us4*)xb)[i] = o;
  } else {
    const int j = i - n_x4;            // 0..196607
    const int sel = j >> 16;           // which weight (65536 float4 each)
    const int off4 = j & 65535;
    const float* wsrc = (sel == 0) ? wq : ((sel == 1) ? wk : wv);
    const float scale = (sel == 0) ? 0.36067376022224085f : 1.0f;
    float4v v = ((const float4v*)wsrc)[off4];
    us4 o;
    o[0] = f2bf(v[0] * scale); o[1] = f2bf(v[1] * scale);
    o[2] = f2bf(v[2] * scale); o[3] = f2bf(v[3] * scale);
    ((us4*)wb)[(sel << 16) + off4] = o;
  }
}

// ---------------- Kernel B: projection GEMM  Y[s,f] = sum_d x[s,b,d] * w[f,d] ---------
// grid: (8 M-tiles, 4 N-tiles, 48 = b*3+wsel). 128x128 tile, BK=32, 4 waves of 64x64.
// Outputs: wsel 0/1 -> q/k as [bh][s][e] bf16 ; wsel 2 -> vT as [bh][e][s] bf16.
__global__ __launch_bounds__(256) void proj_kernel(
    const unsigned short* __restrict__ xb,
    const unsigned short* __restrict__ wb,
    unsigned short* __restrict__ qb,
    unsigned short* __restrict__ kb,
    unsigned short* __restrict__ vt) {
  const int bm = blockIdx.x * 128;
  const int bn = blockIdx.y * 128;
  const int b = blockIdx.z / 3;
  const int wsel = blockIdx.z % 3;

  __shared__ unsigned short At[128 * 32];
  __shared__ unsigned short Bt[128 * 32];
  __shared__ unsigned short OT[4][64 * 72];   // per-wave 64x64 transpose pad +8

  const int tid = threadIdx.x;
  const int w = tid >> 6;
  const int lane = tid & 63;

  const unsigned short* wptr = wb + wsel * (512 * DD);

  f32x4 acc[4][4];
#pragma unroll
  for (int mi = 0; mi < 4; ++mi)
#pragma unroll
    for (int ni = 0; ni < 4; ++ni) acc[mi][ni] = (f32x4){0.f, 0.f, 0.f, 0.f};

  const int m0 = (w & 1) * 64;
  const int n0 = (w >> 1) * 64;

  for (int kt = 0; kt < 16; ++kt) {
#pragma unroll
    for (int i = 0; i < 2; ++i) {
      const int idx8 = i * 256 + tid;        // 0..511 : r = idx8/4, c8 = idx8%4
      const int r = idx8 >> 2;
      const int c8 = idx8 & 3;
      GLDS16(&At[(i * 256 + w * 64) * 8],
             xb + (size_t)(bm + r) * (BB * DD) + b * DD + kt * 32 + c8 * 8);
      GLDS16(&Bt[(i * 256 + w * 64) * 8],
             wptr + (size_t)(bn + r) * DD + kt * 32 + c8 * 8);
    }
    __syncthreads();
    bf16x8 af[4], bfr[4];
#pragma unroll
    for (int mi = 0; mi < 4; ++mi)
      af[mi] = *(const bf16x8*)&At[(m0 + mi * 16 + (lane & 15)) * 32 + (lane >> 4) * 8];
#pragma unroll
    for (int ni = 0; ni < 4; ++ni)
      bfr[ni] = *(const bf16x8*)&Bt[(n0 + ni * 16 + (lane & 15)) * 32 + (lane >> 4) * 8];
#pragma unroll
    for (int mi = 0; mi < 4; ++mi)
#pragma unroll
      for (int ni = 0; ni < 4; ++ni)
        acc[mi][ni] =
            __builtin_amdgcn_mfma_f32_16x16x32_bf16(af[mi], bfr[ni], acc[mi][ni], 0, 0, 0);
    __syncthreads();
  }

  // epilogue: per-wave LDS transpose, then coalesced 16B global stores
  const int h = (bn + n0) >> 6;                 // wave's 64 features = exactly one head
  unsigned short* OTw = &OT[w][0];
  if (wsel != 2) {
    // OT[row=s_local][col=e]
#pragma unroll
    for (int mi = 0; mi < 4; ++mi)
#pragma unroll
      for (int ni = 0; ni < 4; ++ni)
#pragma unroll
        for (int j = 0; j < 4; ++j)
          OTw[(mi * 16 + (lane >> 4) * 4 + j) * 72 + ni * 16 + (lane & 15)] =
              f2bf(acc[mi][ni][j]);
  } else {
    // OT[row=e][col=s_local]  (transposed store, 4 consecutive s pack to 8B)
#pragma unroll
    for (int mi = 0; mi < 4; ++mi)
#pragma unroll
      for (int ni = 0; ni < 4; ++ni) {
        us4 pk;
#pragma unroll
        for (int j = 0; j < 4; ++j) pk[j] = f2bf(acc[mi][ni][j]);
        *(us4*)&OTw[(ni * 16 + (lane & 15)) * 72 + mi * 16 + (lane >> 4) * 4] = pk;
      }
  }
  unsigned short* gout = (wsel == 0) ? qb : ((wsel == 1) ? kb : vt);
#pragma unroll
  for (int pass = 0; pass < 8; ++pass) {
    const int row = pass * 8 + (lane >> 3);
    bf16x8 vrow = *(const bf16x8*)&OTw[row * 72 + (lane & 7) * 8];
    size_t dst;
    if (wsel != 2)
      dst = ((size_t)(b * HH + h) * SS + (size_t)(bm + m0 + row)) * DHH + (lane & 7) * 8;
    else
      dst = ((size_t)(b * HH + h) * DHH + (size_t)row) * SS + (bm + m0) + (lane & 7) * 8;
    *(bf16x8*)&gout[dst] = vrow;
  }
}

// ---------------- Kernel C: fused attention, v4 ---------------------------------------
// 32x32x16 MFMA, 32 q-rows/wave (2x LDS amortization). Swapped QK^T: C[key][q], q=lane&31.
// P relayout in-register: v_perm packs + shfl_xor(32) cross-half exchange. No P LDS.
__global__ __launch_bounds__(512, 4) void attn_kernel(
    const unsigned short* __restrict__ qb,
    const unsigned short* __restrict__ kb,
    const unsigned short* __restrict__ vt,
    const float* __restrict__ mask,
    float* __restrict__ out) {
  // bijective XCD decode: 512 blocks = 8 XCDs x (16 bh x 4 qt)
  const int id = blockIdx.x;
  const int xcd = id & 7;
  const int slot = id >> 3;
  const int bh = xcd * 16 + (slot >> 2);
  const int qt = slot & 3;
  const int b = bh >> 3;
  const int h = bh & 7;
  const int tid = threadIdx.x;
  const int w = tid >> 6;
  const int lane = tid & 63;
  const int l31 = lane & 31;
  const int hi32 = lane >> 5;

  __shared__ float mask_s[SS];
  __shared__ unsigned short Ks[2][64 * 64];    // [key][dh], 128B rows, XOR-swizzled
  __shared__ unsigned short Vs[2][64 * 64];    // [e][key],  128B rows, XOR-swizzled
  __shared__ float rs_s[8][32];                // per-wave rowsum reciprocals

  {
    float2v mv = *(const float2v*)&mask[b * SS + tid * 2];
    mask_s[tid * 2] = mv[0];
    mask_s[tid * 2 + 1] = mv[1];
  }

  const size_t base_qk = (size_t)bh * SS * DHH;
  const int q0 = qt * 256 + w * 32;

  // Q B-frags: aq[ks]: q-row = q0+l31, dh = ks*16 + hi32*8 .. +8
  bf16x8 aq[4];
  {
    const unsigned short* qp = qb + base_qk + (size_t)(q0 + l31) * DHH + hi32 * 8;
    aq[0] = *(const bf16x8*)(qp);
    aq[1] = *(const bf16x8*)(qp + 16);
    aq[2] = *(const bf16x8*)(qp + 32);
    aq[3] = *(const bf16x8*)(qp + 48);
  }

  // staging: wave w fills rows [8w, 8w+8); source col inverse-swizzled, LDS dest linear
  const int srow = w * 8 + (lane >> 3);
  const int sxb = ((lane & 7) << 4) ^ ((srow & 7) << 4);
  const unsigned short* ksrc = kb + base_qk + (size_t)srow * DHH + (sxb >> 1);
  const unsigned short* vsrc = vt + (size_t)bh * DHH * SS + (size_t)srow * SS + (sxb >> 1);

#define STAGE(bb, kt2)                                                    \
  do {                                                                    \
    GLDS16(&Ks[bb][w * 512], ksrc + (size_t)(kt2) * (64 * DHH));          \
    GLDS16(&Vs[bb][w * 512], vsrc + (size_t)(kt2) * 64);                  \
  } while (0)

  STAGE(0, 0);

  f32x16 accO[2];
#pragma unroll
  for (int n = 0; n < 2; ++n)
#pragma unroll
    for (int i = 0; i < 16; ++i) accO[n][i] = 0.f;
  float rs = 0.f;

  __syncthreads();   // drains vmcnt: tile 0 resident; mask_s visible

  int buf = 0;
  for (int kt = 0; kt < 16; ++kt) {
    if (kt < 15) STAGE(buf ^ 1, kt + 1);     // prefetch next tile (in flight all phase)
    const char* Kb = (const char*)&Ks[buf][0];
    const char* Vb = (const char*)&Vs[buf][0];
    const int k0 = kt * 64;

#pragma unroll
    for (int T = 0; T < 2; ++T) {            // two 32-key tiles per kt
      const int krow = T * 32 + l31;
      const int ksw = (krow & 7) << 4;
      f32x16 sc = {};
#pragma unroll
      for (int ks = 0; ks < 4; ++ks) {
        bf16x8 kf = *(const bf16x8*)(Kb + krow * 128 + ((ks * 32 + hi32 * 16) ^ ksw));
        sc = __builtin_amdgcn_mfma_f32_32x32x16_bf16(kf, aq[ks], sc, 0, 0, 0);
      }
      // softmax: p = mask * exp2(-2*log2e / (1 + exp2(sc)))   (Q pre-scaled by 2/(8 ln2))
      unsigned int pu[16];
#pragma unroll
      for (int g = 0; g < 4; ++g) {
        float4v mv = *(const float4v*)&mask_s[k0 + T * 32 + g * 8 + hi32 * 4];
#pragma unroll
        for (int i = 0; i < 4; ++i) {
          float u = __builtin_amdgcn_exp2f(sc[g * 4 + i]);
          float r = __builtin_amdgcn_rcpf(1.f + u);
          float p = mv[i] * __builtin_amdgcn_exp2f(-2.88539008178f * r);
          rs += p;
          union { float f; unsigned int u; } cv;
          cv.f = p;
          pu[g * 4 + i] = cv.u;
        }
      }
      // pack to bf16 pairs (truncate; bias cancels in p*v / sum(p))
      unsigned int wv[8];
#pragma unroll
      for (int m = 0; m < 8; ++m)
        wv[m] = __builtin_amdgcn_perm(pu[2 * m + 1], pu[2 * m], 0x07060302u);
      // cross-half exchange: low lanes need partner w0,w1,w4,w5; high need w2,w3,w6,w7
      unsigned int t0 = hi32 ? wv[0] : wv[2];
      unsigned int t1 = hi32 ? wv[1] : wv[3];
      unsigned int t2 = hi32 ? wv[4] : wv[6];
      unsigned int t3 = hi32 ? wv[5] : wv[7];
      unsigned int s0 = (unsigned int)__shfl_xor((int)t0, 32, 64);
      unsigned int s1 = (unsigned int)__shfl_xor((int)t1, 32, 64);
      unsigned int s2 = (unsigned int)__shfl_xor((int)t2, 32, 64);
      unsigned int s3 = (unsigned int)__shfl_xor((int)t3, 32, 64);
      union { unsigned int u[4]; bf16x8 v; } f0, f1;
      f0.u[0] = hi32 ? s0 : wv[0];
      f0.u[1] = hi32 ? s1 : wv[1];
      f0.u[2] = hi32 ? wv[2] : s0;
      f0.u[3] = hi32 ? wv[3] : s1;
      f1.u[0] = hi32 ? s2 : wv[4];
      f1.u[1] = hi32 ? s3 : wv[5];
      f1.u[2] = hi32 ? wv[6] : s2;
      f1.u[3] = hi32 ? wv[7] : s3;
      // PV: A = P frags (keys T*32+0..15 / +16..31), B = V from swizzled LDS
#pragma unroll
      for (int n = 0; n < 2; ++n) {
        const int vrow = n * 32 + l31;
        const int vsw = (vrow & 7) << 4;
        bf16x8 bv0 = *(const bf16x8*)(Vb + vrow * 128 + (((T * 2 + 0) * 32 + hi32 * 16) ^ vsw));
        bf16x8 bv1 = *(const bf16x8*)(Vb + vrow * 128 + (((T * 2 + 1) * 32 + hi32 * 16) ^ vsw));
        accO[n] = __builtin_amdgcn_mfma_f32_32x32x16_bf16(f0.v, bv0, accO[n], 0, 0, 0);
        accO[n] = __builtin_amdgcn_mfma_f32_32x32x16_bf16(f1.v, bv1, accO[n], 0, 0, 0);
      }
    }
    __syncthreads();   // drains vmcnt (next tile landed) + protects buffer flip
    buf ^= 1;
  }
#undef STAGE

  // rowsum: lane's rs covers its hi32-half of keys for q=l31; combine + invert
  rs += __shfl_xor(rs, 32, 64);
  if (hi32 == 0) rs_s[w][l31] = __builtin_amdgcn_rcpf(rs);
  float4v ri[4];
#pragma unroll
  for (int g = 0; g < 4; ++g) ri[g] = *(const float4v*)&rs_s[w][g * 8 + hi32 * 4];

#pragma unroll
  for (int n = 0; n < 2; ++n)
#pragma unroll
    for (int g = 0; g < 4; ++g)
#pragma unroll
      for (int i = 0; i < 4; ++i) {
        const int qrow = q0 + g * 8 + hi32 * 4 + i;
        out[((size_t)qrow * BB + b) * DD + h * DHH + n * 32 + l31] =
            accO[n][g * 4 + i] * ri[g][i];
      }
}

extern "C" void kernel_launch(void* const* d_in, const int* in_sizes, int n_in,
                              void* d_out, int out_size, void* d_ws, size_t ws_size,
                              hipStream_t stream) {
  const float* x = (const float*)d_in[0];
  const float* mask = (const float*)d_in[1];
  const float* wq = (const float*)d_in[2];
  const float* wk = (const float*)d_in[3];
  const float* wv = (const float*)d_in[4];
  float* out = (float*)d_out;

  char* ws = (char*)d_ws;
  unsigned short* xb = (unsigned short*)(ws);                         // 16 MB
  unsigned short* wb = (unsigned short*)(ws + (16ull << 20));         // 1.5 MB (pad 2)
  unsigned short* qb = (unsigned short*)(ws + (18ull << 20));         // 16 MB
  unsigned short* kb = (unsigned short*)(ws + (34ull << 20));         // 16 MB
  unsigned short* vt = (unsigned short*)(ws + (50ull << 20));         // 16 MB -> 66 MB

  cvt_kernel<<<dim3(8960), 256, 0, stream>>>(x, wq, wk, wv, xb, wb);
  proj_kernel<<<dim3(8, 4, 48), 256, 0, stream>>>(xb, wb, qb, kb, vt);
  attn_kernel<<<dim3(512), 512, 0, stream>>>(qb, kb, vt, mask, out);
}